// Round 3
// baseline (432.212 us; speedup 1.0000x reference)
//
#include <hip/hip_runtime.h>

typedef __attribute__((ext_vector_type(8))) short short8;
typedef __attribute__((ext_vector_type(4))) float f32x4;

#define N_PTS   100000
#define N_CELLS 274625            // 65^3
#define GB_ELEMS (N_CELLS * 32)   // both grids, channel-interleaved

static __device__ __forceinline__ unsigned short f2bf(float f) {
    unsigned int u = __builtin_bit_cast(unsigned int, f);
    u += 0x7fffu + ((u >> 16) & 1u);   // round-to-nearest-even
    return (unsigned short)(u >> 16);
}
static __device__ __forceinline__ float bflo(unsigned int u) {
    return __builtin_bit_cast(float, u << 16);
}
static __device__ __forceinline__ float bfhi(unsigned int u) {
    return __builtin_bit_cast(float, u & 0xffff0000u);
}

// ---------------- P1: grids f32 -> bf16, channel-interleaved [cell][32] -----
__global__ __launch_bounds__(256) void prep_grids(
        const float* __restrict__ g0, const float* __restrict__ g1,
        unsigned short* __restrict__ gb) {
    int tid = blockIdx.x * 256 + threadIdx.x;
    if (tid >= GB_ELEMS) return;
    int c = tid & 31, cell = tid >> 5;
    float v = (c < 16) ? g0[cell * 16 + c] : g1[cell * 16 + (c - 16)];
    gb[tid] = f2bf(v);
}

// ---------------- P2: weights f32 -> bf16, transposed Wt[n][k] --------------
__global__ __launch_bounds__(256) void prep_weights(
        const float* __restrict__ ligW, const float* __restrict__ recW,
        const float* __restrict__ w1, const float* __restrict__ w2,
        const float* __restrict__ wf,
        unsigned short* __restrict__ ligWt, unsigned short* __restrict__ recWt,
        unsigned short* __restrict__ w1t, unsigned short* __restrict__ w2t,
        unsigned short* __restrict__ wft) {
    int tid = blockIdx.x * 256 + threadIdx.x;
    if (tid < 4096) {                       // ligWt [128][32], K padded 16->32
        int n = tid >> 5, k = tid & 31;
        ligWt[tid] = (k < 16) ? f2bf(ligW[k * 128 + n]) : (unsigned short)0;
    } else if (tid < 8192) {                // recWt [128][32]
        int e = tid - 4096; int n = e >> 5, k = e & 31;
        recWt[e] = f2bf(recW[k * 128 + n]);
    } else if (tid < 24576) {               // w1t [128][128]
        int e = tid - 8192; int n = e >> 7, k = e & 127;
        w1t[e] = f2bf(w1[k * 128 + n]);
    } else if (tid < 40960) {               // w2t [128][128]
        int e = tid - 24576; int n = e >> 7, k = e & 127;
        w2t[e] = f2bf(w2[k * 128 + n]);
    } else if (tid < 139264) {              // wft [256][384]
        int e = tid - 40960; int n = e / 384, k = e - n * 384;
        wft[e] = f2bf(wf[k * 256 + n]);
    }
}

// ---------------- A: B-spline interpolation + nb conversion -----------------
__global__ __launch_bounds__(256) void interp_kernel(
        const float* __restrict__ pos, const float* __restrict__ nb,
        const unsigned short* __restrict__ gb,
        unsigned short* __restrict__ nbb, unsigned short* __restrict__ reccat) {
    int i = blockIdx.x * 256 + threadIdx.x;
    if (i >= N_PTS) return;

    // nb_params row -> bf16
    {
        const float4* np4 = (const float4*)(nb + (size_t)i * 16);
        unsigned int pk[8];
        #pragma unroll
        for (int j = 0; j < 4; j++) {
            float4 vv = np4[j];
            pk[j*2+0] = (unsigned)f2bf(vv.x) | ((unsigned)f2bf(vv.y) << 16);
            pk[j*2+1] = (unsigned)f2bf(vv.z) | ((unsigned)f2bf(vv.w) << 16);
        }
        uint4* dst = (uint4*)(nbb + (size_t)i * 16);
        dst[0] = make_uint4(pk[0], pk[1], pk[2], pk[3]);
        dst[1] = make_uint4(pk[4], pk[5], pk[6], pk[7]);
    }

    // spline weights + clamped indices per axis
    float w[3][4]; int jj[3][4];
    #pragma unroll
    for (int a = 0; a < 3; a++) {
        float p = pos[(size_t)i * 3 + a];
        float pn = fminf(fmaxf(0.5f + p * 0.03125f, 0.0f), 1.0f);
        float u = pn * 64.0f;
        float fl = floorf(u);
        int i0 = (int)fl;
        float t = u - fl;
        float t2 = t * t, t3 = t2 * t;
        w[a][0] = (1.0f - 3.0f*t + 3.0f*t2 - t3) * (1.0f/6.0f);
        w[a][1] = (4.0f - 6.0f*t2 + 3.0f*t3) * (1.0f/6.0f);
        w[a][2] = (1.0f + 3.0f*t + 3.0f*t2 - 3.0f*t3) * (1.0f/6.0f);
        w[a][3] = t3 * (1.0f/6.0f);
        jj[a][0] = max(i0 - 1, 0);
        jj[a][1] = i0;
        jj[a][2] = min(i0 + 1, 64);
        jj[a][3] = min(i0 + 2, 64);
    }

    float acc[32];
    #pragma unroll
    for (int c = 0; c < 32; c++) acc[c] = 0.0f;

    for (int ax = 0; ax < 4; ax++) {
        int xoff = jj[0][ax] * 4225;           // 65*65
        for (int ay = 0; ay < 4; ay++) {
            float wxy = w[0][ax] * w[1][ay];
            int xy = xoff + jj[1][ay] * 65;
            #pragma unroll
            for (int az = 0; az < 4; az++) {
                float ww = wxy * w[2][az];
                const uint4* p = (const uint4*)(gb + ((size_t)(xy + jj[2][az]) << 5));
                uint4 q0 = p[0], q1 = p[1], q2 = p[2], q3 = p[3];
                unsigned int vv[16] = {q0.x,q0.y,q0.z,q0.w, q1.x,q1.y,q1.z,q1.w,
                                       q2.x,q2.y,q2.z,q2.w, q3.x,q3.y,q3.z,q3.w};
                #pragma unroll
                for (int h = 0; h < 16; h++) {
                    acc[2*h]   = fmaf(ww, bflo(vv[h]), acc[2*h]);
                    acc[2*h+1] = fmaf(ww, bfhi(vv[h]), acc[2*h+1]);
                }
            }
        }
    }

    unsigned int rk[16];
    #pragma unroll
    for (int h = 0; h < 16; h++)
        rk[h] = (unsigned)f2bf(acc[2*h]) | ((unsigned)f2bf(acc[2*h+1]) << 16);
    uint4* rdst = (uint4*)(reccat + (size_t)i * 32);
    rdst[0] = make_uint4(rk[0],  rk[1],  rk[2],  rk[3]);
    rdst[1] = make_uint4(rk[4],  rk[5],  rk[6],  rk[7]);
    rdst[2] = make_uint4(rk[8],  rk[9],  rk[10], rk[11]);
    rdst[3] = make_uint4(rk[12], rk[13], rk[14], rk[15]);
}

// ---------------- B: fully fused MLP via bf16 MFMA --------------------------
// One wave handles one 16-point M-tile. D layout: row=(lane>>4)*4+reg, col=lane&15.
// D->A re-layout goes through a per-wave LDS tile with XOR swizzle (G4).
__global__ __launch_bounds__(128) void fused_mlp(
        const unsigned short* __restrict__ nbb,
        const unsigned short* __restrict__ reccat,
        const unsigned short* __restrict__ ligWt,
        const unsigned short* __restrict__ recWt,
        const unsigned short* __restrict__ w1t,
        const unsigned short* __restrict__ w2t,
        const unsigned short* __restrict__ wft,
        const float* __restrict__ lig_b, const float* __restrict__ rec_b,
        const float* __restrict__ b1, const float* __restrict__ b2,
        const float* __restrict__ fb, float* __restrict__ out) {
    int w = threadIdx.x >> 6;
    int lane = threadIdx.x & 63;
    int r = lane & 15, q = lane >> 4;
    int tile = blockIdx.x * 2 + w;       // grid sized exactly: no guard needed
    int m0 = tile * 16;
    int xmask = (r & 7) << 3;

    __shared__ unsigned short lsh[2][3][2048];   // 2 waves x {ligx, recx, both}
    unsigned short* Lx = lsh[w][0];
    unsigned short* Rx = lsh[w][1];
    unsigned short* Bx = lsh[w][2];

    // A fragments: nb (K=16 padded to 32) and rec_cat (K=32)
    short8 aN = {0, 0, 0, 0, 0, 0, 0, 0};
    if (q < 2) aN = *(const short8*)(nbb + (size_t)(m0 + r) * 16 + q * 8);
    short8 aC = *(const short8*)(reccat + (size_t)(m0 + r) * 32 + q * 8);

    // lig_x = nb@ligW + b ; rec_x = reccat@recW + b  -> LDS (bf16, swizzled)
    #pragma unroll
    for (int nt = 0; nt < 8; nt++) {
        int n = nt * 16 + r;
        float bL = lig_b[n], bR = rec_b[n];
        f32x4 dL = {bL, bL, bL, bL};
        f32x4 dR = {bR, bR, bR, bR};
        short8 bN = *(const short8*)(ligWt + n * 32 + q * 8);
        short8 bC = *(const short8*)(recWt + n * 32 + q * 8);
        dL = __builtin_amdgcn_mfma_f32_16x16x32_bf16(aN, bN, dL, 0, 0, 0);
        dR = __builtin_amdgcn_mfma_f32_16x16x32_bf16(aC, bC, dR, 0, 0, 0);
        #pragma unroll
        for (int j = 0; j < 4; j++) {
            int row = q * 4 + j;
            int sw = (row & 7) << 3;
            Lx[row * 128 + (n ^ sw)] = f2bf(dL[j]);
            Rx[row * 128 + (n ^ sw)] = f2bf(dR[j]);
        }
    }
    __syncthreads();

    short8 aL[4], aR[4];
    #pragma unroll
    for (int ks = 0; ks < 4; ks++) {
        int c = (ks * 32 + q * 8) ^ xmask;
        aL[ks] = *(const short8*)(Lx + r * 128 + c);
        aR[ks] = *(const short8*)(Rx + r * 128 + c);
    }

    // both = (lig_x@W1 + b1) * (rec_x@W2 + b2) -> LDS
    #pragma unroll
    for (int nt = 0; nt < 8; nt++) {
        int n = nt * 16 + r;
        float c1 = b1[n], c2 = b2[n];
        f32x4 uL = {c1, c1, c1, c1};
        f32x4 uR = {c2, c2, c2, c2};
        const unsigned short* w1r = w1t + n * 128;
        const unsigned short* w2r = w2t + n * 128;
        #pragma unroll
        for (int ks = 0; ks < 4; ks++) {
            uL = __builtin_amdgcn_mfma_f32_16x16x32_bf16(aL[ks], *(const short8*)(w1r + ks * 32 + q * 8), uL, 0, 0, 0);
            uR = __builtin_amdgcn_mfma_f32_16x16x32_bf16(aR[ks], *(const short8*)(w2r + ks * 32 + q * 8), uR, 0, 0, 0);
        }
        #pragma unroll
        for (int j = 0; j < 4; j++) {
            int row = q * 4 + j;
            int sw = (row & 7) << 3;
            Bx[row * 128 + (n ^ sw)] = f2bf(uL[j] * uR[j]);
        }
    }
    __syncthreads();

    short8 aB[4];
    #pragma unroll
    for (int ks = 0; ks < 4; ks++) {
        int c = (ks * 32 + q * 8) ^ xmask;
        aB[ks] = *(const short8*)(Bx + r * 128 + c);
    }

    // out = [lig_x, rec_x, both] @ final_W + final_b
    #pragma unroll 4
    for (int nt = 0; nt < 16; nt++) {
        int n = nt * 16 + r;
        float cb = fb[n];
        f32x4 o = {cb, cb, cb, cb};
        const unsigned short* wr = wft + (size_t)n * 384;
        #pragma unroll
        for (int ks = 0; ks < 4; ks++)
            o = __builtin_amdgcn_mfma_f32_16x16x32_bf16(aL[ks], *(const short8*)(wr + ks * 32 + q * 8), o, 0, 0, 0);
        #pragma unroll
        for (int ks = 0; ks < 4; ks++)
            o = __builtin_amdgcn_mfma_f32_16x16x32_bf16(aR[ks], *(const short8*)(wr + 128 + ks * 32 + q * 8), o, 0, 0, 0);
        #pragma unroll
        for (int ks = 0; ks < 4; ks++)
            o = __builtin_amdgcn_mfma_f32_16x16x32_bf16(aB[ks], *(const short8*)(wr + 256 + ks * 32 + q * 8), o, 0, 0, 0);
        float* op = out + (size_t)(m0 + q * 4) * 256 + n;
        op[0] = o[0]; op[256] = o[1]; op[512] = o[2]; op[768] = o[3];
    }
}

extern "C" void kernel_launch(void* const* d_in, const int* in_sizes, int n_in,
                              void* d_out, int out_size, void* d_ws, size_t ws_size,
                              hipStream_t stream) {
    const float* pos   = (const float*)d_in[0];
    const float* nb    = (const float*)d_in[1];
    // d_in[2] = batch: unused by the reference
    const float* g0    = (const float*)d_in[3];
    const float* g1    = (const float*)d_in[4];
    const float* ligW  = (const float*)d_in[5];
    const float* lig_b = (const float*)d_in[6];
    const float* recW  = (const float*)d_in[7];
    const float* rec_b = (const float*)d_in[8];
    const float* w1    = (const float*)d_in[9];
    const float* b1    = (const float*)d_in[10];
    const float* w2    = (const float*)d_in[11];
    const float* b2    = (const float*)d_in[12];
    const float* wf    = (const float*)d_in[13];
    const float* fbias = (const float*)d_in[14];
    float* out = (float*)d_out;

    char* ws = (char*)d_ws;
    size_t off = 0;
    auto alloc = [&](size_t bytes) {
        char* p = ws + off;
        off = (off + bytes + 255) & ~(size_t)255;
        return p;
    };
    unsigned short* gb     = (unsigned short*)alloc((size_t)GB_ELEMS * 2);   // 17.6 MB
    unsigned short* nbb    = (unsigned short*)alloc((size_t)N_PTS * 16 * 2); // 3.2 MB
    unsigned short* reccat = (unsigned short*)alloc((size_t)N_PTS * 32 * 2); // 6.4 MB
    unsigned short* ligWt  = (unsigned short*)alloc(4096 * 2);
    unsigned short* recWt  = (unsigned short*)alloc(4096 * 2);
    unsigned short* w1t    = (unsigned short*)alloc(16384 * 2);
    unsigned short* w2t    = (unsigned short*)alloc(16384 * 2);
    unsigned short* wft    = (unsigned short*)alloc(98304 * 2);

    hipLaunchKernelGGL(prep_grids, dim3((GB_ELEMS + 255) / 256), dim3(256), 0, stream,
                       g0, g1, gb);
    hipLaunchKernelGGL(prep_weights, dim3((139264 + 255) / 256), dim3(256), 0, stream,
                       ligW, recW, w1, w2, wf, ligWt, recWt, w1t, w2t, wft);
    hipLaunchKernelGGL(interp_kernel, dim3((N_PTS + 255) / 256), dim3(256), 0, stream,
                       pos, nb, gb, nbb, reccat);
    hipLaunchKernelGGL(fused_mlp, dim3(N_PTS / 32), dim3(128), 0, stream,
                       nbb, reccat, ligWt, recWt, w1t, w2t, wft,
                       lig_b, rec_b, b1, b2, fbias, out);
}

// Round 5
// 323.682 us; speedup vs baseline: 1.3353x; 1.3353x over previous
//
#include <hip/hip_runtime.h>

typedef __attribute__((ext_vector_type(8))) short short8;
typedef __attribute__((ext_vector_type(4))) float f32x4;

#define N_PTS    100000
#define N_ROWS_P 100096           // padded to 782*128 for fused tiling
#define N_CELLS  274625           // 65^3
#define GB_ELEMS (N_CELLS * 32)   // both grids, channel-interleaved

static __device__ __forceinline__ unsigned short f2bf(float f) {
    unsigned int u = __builtin_bit_cast(unsigned int, f);
    u += 0x7fffu + ((u >> 16) & 1u);   // round-to-nearest-even
    return (unsigned short)(u >> 16);
}
static __device__ __forceinline__ float bflo(unsigned int u) {
    return __builtin_bit_cast(float, u << 16);
}
static __device__ __forceinline__ float bfhi(unsigned int u) {
    return __builtin_bit_cast(float, u & 0xffff0000u);
}
static __device__ __forceinline__ unsigned long long pack4bf(f32x4 v) {
    return (unsigned long long)f2bf(v[0])
         | ((unsigned long long)f2bf(v[1]) << 16)
         | ((unsigned long long)f2bf(v[2]) << 32)
         | ((unsigned long long)f2bf(v[3]) << 48);
}

// ---------------- P1: grids f32 -> bf16, channel-interleaved [cell][32] -----
// tid -> (cell, chunk of 4 channels); float4 read, u64 write.
__global__ __launch_bounds__(256) void prep_grids(
        const float* __restrict__ g0, const float* __restrict__ g1,
        unsigned short* __restrict__ gb) {
    int tid = blockIdx.x * 256 + threadIdx.x;
    if (tid >= N_CELLS * 8) return;
    int chunk = tid & 7, cell = tid >> 3;
    const float* src = (chunk < 4) ? (g0 + (size_t)cell * 16 + chunk * 4)
                                   : (g1 + (size_t)cell * 16 + (chunk - 4) * 4);
    float4 v = *(const float4*)src;
    unsigned long long pk = (unsigned long long)f2bf(v.x)
                          | ((unsigned long long)f2bf(v.y) << 16)
                          | ((unsigned long long)f2bf(v.z) << 32)
                          | ((unsigned long long)f2bf(v.w) << 48);
    *(unsigned long long*)(gb + (size_t)cell * 32 + chunk * 4) = pk;
}

// ---------------- P2: weights f32 -> bf16, transposed Wt[n][k] --------------
__global__ __launch_bounds__(256) void prep_weights(
        const float* __restrict__ ligW, const float* __restrict__ recW,
        const float* __restrict__ w1, const float* __restrict__ w2,
        const float* __restrict__ wf,
        unsigned short* __restrict__ ligWt, unsigned short* __restrict__ recWt,
        unsigned short* __restrict__ w1t, unsigned short* __restrict__ w2t,
        unsigned short* __restrict__ wft) {
    int tid = blockIdx.x * 256 + threadIdx.x;
    if (tid < 4096) {                       // ligWt [128][32], K padded 16->32
        int n = tid >> 5, k = tid & 31;
        ligWt[tid] = (k < 16) ? f2bf(ligW[k * 128 + n]) : (unsigned short)0;
    } else if (tid < 8192) {                // recWt [128][32]
        int e = tid - 4096; int n = e >> 5, k = e & 31;
        recWt[e] = f2bf(recW[k * 128 + n]);
    } else if (tid < 24576) {               // w1t [128][128]
        int e = tid - 8192; int n = e >> 7, k = e & 127;
        w1t[e] = f2bf(w1[k * 128 + n]);
    } else if (tid < 40960) {               // w2t [128][128]
        int e = tid - 24576; int n = e >> 7, k = e & 127;
        w2t[e] = f2bf(w2[k * 128 + n]);
    } else if (tid < 139264) {              // wft [256][384]
        int e = tid - 40960; int n = e / 384, k = e - n * 384;
        wft[e] = f2bf(wf[k * 256 + n]);
    }
}

// ---------------- A: B-spline interpolation, 4 lanes per point --------------
// lane sub = az tap; 16 (ax,ay) iterations per lane; xor-shuffle reduce.
__global__ __launch_bounds__(256) void interp_kernel(
        const float* __restrict__ pos, const float* __restrict__ nb,
        const unsigned short* __restrict__ gb,
        unsigned short* __restrict__ nbb, unsigned short* __restrict__ reccat) {
    int tid = blockIdx.x * 256 + threadIdx.x;
    int pt = tid >> 2;
    int sub = tid & 3;
    if (pt >= N_PTS) return;

    // nb_params: lane sub converts 4 floats -> 8B store
    {
        float4 v = *(const float4*)(nb + (size_t)pt * 16 + sub * 4);
        unsigned long long pk = (unsigned long long)f2bf(v.x)
                              | ((unsigned long long)f2bf(v.y) << 16)
                              | ((unsigned long long)f2bf(v.z) << 32)
                              | ((unsigned long long)f2bf(v.w) << 48);
        *(unsigned long long*)(nbb + (size_t)pt * 16 + sub * 4) = pk;
    }

    // spline weights + clamped indices per axis (computed redundantly per lane)
    float w[3][4]; int jj[3][4];
    #pragma unroll
    for (int a = 0; a < 3; a++) {
        float p = pos[(size_t)pt * 3 + a];
        float pn = fminf(fmaxf(0.5f + p * 0.03125f, 0.0f), 1.0f);
        float u = pn * 64.0f;
        float fl = floorf(u);
        int i0 = (int)fl;
        float t = u - fl;
        float t2 = t * t, t3 = t2 * t;
        w[a][0] = (1.0f - 3.0f*t + 3.0f*t2 - t3) * (1.0f/6.0f);
        w[a][1] = (4.0f - 6.0f*t2 + 3.0f*t3) * (1.0f/6.0f);
        w[a][2] = (1.0f + 3.0f*t + 3.0f*t2 - 3.0f*t3) * (1.0f/6.0f);
        w[a][3] = t3 * (1.0f/6.0f);
        jj[a][0] = max(i0 - 1, 0);
        jj[a][1] = i0;
        jj[a][2] = min(i0 + 1, 64);
        jj[a][3] = min(i0 + 2, 64);
    }

    float wz = w[2][sub];
    int jz = jj[2][sub];

    float acc[32];
    #pragma unroll
    for (int c = 0; c < 32; c++) acc[c] = 0.0f;

    #pragma unroll
    for (int ax = 0; ax < 4; ax++) {
        int xoff = jj[0][ax] * 4225;           // 65*65
        float wx = w[0][ax];
        #pragma unroll
        for (int ay = 0; ay < 4; ay++) {
            float ww = wx * w[1][ay] * wz;
            const uint4* p = (const uint4*)(gb + ((size_t)(xoff + jj[1][ay] * 65 + jz) << 5));
            uint4 q0 = p[0], q1 = p[1], q2 = p[2], q3 = p[3];
            unsigned int vv[16] = {q0.x,q0.y,q0.z,q0.w, q1.x,q1.y,q1.z,q1.w,
                                   q2.x,q2.y,q2.z,q2.w, q3.x,q3.y,q3.z,q3.w};
            #pragma unroll
            for (int h = 0; h < 16; h++) {
                acc[2*h]   = fmaf(ww, bflo(vv[h]), acc[2*h]);
                acc[2*h+1] = fmaf(ww, bfhi(vv[h]), acc[2*h+1]);
            }
        }
    }

    // reduce across the 4-lane group
    #pragma unroll
    for (int c = 0; c < 32; c++) {
        acc[c] += __shfl_xor(acc[c], 1);
        acc[c] += __shfl_xor(acc[c], 2);
    }

    // lane sub writes channels sub*8 .. sub*8+7 (16B store; group covers 64B)
    unsigned int rk[4];
    #pragma unroll
    for (int h = 0; h < 4; h++) {
        int c = sub * 8 + 2 * h;
        rk[h] = (unsigned)f2bf(acc[c]) | ((unsigned)f2bf(acc[c+1]) << 16);
    }
    *(uint4*)(reccat + (size_t)pt * 32 + sub * 8) = make_uint4(rk[0], rk[1], rk[2], rk[3]);
}

// ---------------- B: fused MLP as a 3-phase block-GEMM ----------------------
// Block = 512 thr (8 waves, 2M x 4N), covers 128 rows. Activations [128][384]
// bf16 live in a 96 KB XOR-swizzled LDS tile. MFMA operands SWAPPED
// (mfma(Wfrag, actfrag)) so D is n-contiguous per lane: value j <-> n=base+q*4+j.
#define ACT_ADDR(row, kbyte) ((row) * 768 + ((kbyte) ^ (((row) & 7) << 4)))

__global__ __launch_bounds__(512) void fused_mlp(
        const unsigned short* __restrict__ nbb,
        const unsigned short* __restrict__ reccat,
        const unsigned short* __restrict__ ligWt,
        const unsigned short* __restrict__ recWt,
        const unsigned short* __restrict__ w1t,
        const unsigned short* __restrict__ w2t,
        const unsigned short* __restrict__ wft,
        const float* __restrict__ lig_b, const float* __restrict__ rec_b,
        const float* __restrict__ b1, const float* __restrict__ b2,
        const float* __restrict__ fb, float* __restrict__ out) {
    __shared__ __align__(16) char actB[128 * 768];   // 96 KB

    int w = threadIdx.x >> 6, lane = threadIdx.x & 63;
    int r = lane & 15, q = lane >> 4;
    int wm = w >> 2, wn = w & 3;           // 2M x 4N wave grid
    int mrow0 = blockIdx.x * 128;          // global row base (padded arrays)
    int nf0 = wn * 32;                     // phase-0/1 col base (2 n-frags)

    // ---- phase 0: lig_x = nb@ligW+b, rec_x = reccat@recW+b -> LDS ----
    {
        short8 bN[4], bC[4];
        #pragma unroll
        for (int mf = 0; mf < 4; mf++) {
            int row = mrow0 + wm * 64 + mf * 16 + r;
            short8 z = {0,0,0,0,0,0,0,0};
            bN[mf] = (q < 2) ? *(const short8*)(nbb + (size_t)row * 16 + q * 8) : z;
            bC[mf] = *(const short8*)(reccat + (size_t)row * 32 + q * 8);
        }
        #pragma unroll
        for (int nf = 0; nf < 2; nf++) {
            int n = nf0 + nf * 16 + r;
            short8 aWl = *(const short8*)(ligWt + n * 32 + q * 8);
            short8 aWr = *(const short8*)(recWt + n * 32 + q * 8);
            f32x4 bl4 = *(const f32x4*)(lig_b + nf0 + nf * 16 + q * 4);
            f32x4 br4 = *(const f32x4*)(rec_b + nf0 + nf * 16 + q * 4);
            #pragma unroll
            for (int mf = 0; mf < 4; mf++) {
                int row_l = wm * 64 + mf * 16 + r;
                int kb = (nf0 + nf * 16 + q * 4) * 2;
                f32x4 dL = __builtin_amdgcn_mfma_f32_16x16x32_bf16(aWl, bN[mf], bl4, 0, 0, 0);
                f32x4 dR = __builtin_amdgcn_mfma_f32_16x16x32_bf16(aWr, bC[mf], br4, 0, 0, 0);
                *(unsigned long long*)(actB + ACT_ADDR(row_l, kb))       = pack4bf(dL);
                *(unsigned long long*)(actB + ACT_ADDR(row_l, 256 + kb)) = pack4bf(dR);
            }
        }
    }
    __syncthreads();

    // ---- phase 1: both = (lig@W1+b1)*(rec@W2+b2) -> LDS cols 512..767 ----
    {
        #pragma unroll
        for (int nf = 0; nf < 2; nf++) {
            int n = nf0 + nf * 16 + r;
            short8 a1[4], a2[4];
            #pragma unroll
            for (int ks = 0; ks < 4; ks++) {
                a1[ks] = *(const short8*)(w1t + n * 128 + ks * 32 + q * 8);
                a2[ks] = *(const short8*)(w2t + n * 128 + ks * 32 + q * 8);
            }
            f32x4 c1 = *(const f32x4*)(b1 + nf0 + nf * 16 + q * 4);
            f32x4 c2 = *(const f32x4*)(b2 + nf0 + nf * 16 + q * 4);
            #pragma unroll
            for (int mf = 0; mf < 4; mf++) {
                int row_l = wm * 64 + mf * 16 + r;
                f32x4 u1 = c1, u2 = c2;
                #pragma unroll
                for (int ks = 0; ks < 4; ks++) {
                    short8 bl = *(const short8*)(actB + ACT_ADDR(row_l, ks * 64 + q * 16));
                    short8 br = *(const short8*)(actB + ACT_ADDR(row_l, 256 + ks * 64 + q * 16));
                    u1 = __builtin_amdgcn_mfma_f32_16x16x32_bf16(a1[ks], bl, u1, 0, 0, 0);
                    u2 = __builtin_amdgcn_mfma_f32_16x16x32_bf16(a2[ks], br, u2, 0, 0, 0);
                }
                f32x4 pr = u1 * u2;
                int kb = 512 + (nf0 + nf * 16 + q * 4) * 2;
                *(unsigned long long*)(actB + ACT_ADDR(row_l, kb)) = pack4bf(pr);
            }
        }
    }
    __syncthreads();

    // ---- phase 2: out = [lig|rec|both] @ final_W + fb ----
    {
        f32x4 acc[4][4];
        #pragma unroll
        for (int nf = 0; nf < 4; nf++) {
            f32x4 fb4 = *(const f32x4*)(fb + wn * 64 + nf * 16 + q * 4);
            #pragma unroll
            for (int mf = 0; mf < 4; mf++) acc[mf][nf] = fb4;
        }
        #pragma unroll 4
        for (int ks = 0; ks < 12; ks++) {
            short8 bact[4];
            #pragma unroll
            for (int mf = 0; mf < 4; mf++)
                bact[mf] = *(const short8*)(actB + ACT_ADDR(wm * 64 + mf * 16 + r, ks * 64 + q * 16));
            #pragma unroll
            for (int nf = 0; nf < 4; nf++) {
                int n = wn * 64 + nf * 16 + r;
                short8 aw = *(const short8*)(wft + (size_t)n * 384 + ks * 32 + q * 8);
                #pragma unroll
                for (int mf = 0; mf < 4; mf++)
                    acc[mf][nf] = __builtin_amdgcn_mfma_f32_16x16x32_bf16(aw, bact[mf], acc[mf][nf], 0, 0, 0);
            }
        }
        #pragma unroll
        for (int mf = 0; mf < 4; mf++) {
            int grow = mrow0 + wm * 64 + mf * 16 + r;
            if (grow < N_PTS) {
                float* op = out + (size_t)grow * 256 + wn * 64 + q * 4;
                #pragma unroll
                for (int nf = 0; nf < 4; nf++)
                    *(f32x4*)(op + nf * 16) = acc[mf][nf];
            }
        }
    }
}

extern "C" void kernel_launch(void* const* d_in, const int* in_sizes, int n_in,
                              void* d_out, int out_size, void* d_ws, size_t ws_size,
                              hipStream_t stream) {
    const float* pos   = (const float*)d_in[0];
    const float* nb    = (const float*)d_in[1];
    // d_in[2] = batch: unused by the reference
    const float* g0    = (const float*)d_in[3];
    const float* g1    = (const float*)d_in[4];
    const float* ligW  = (const float*)d_in[5];
    const float* lig_b = (const float*)d_in[6];
    const float* recW  = (const float*)d_in[7];
    const float* rec_b = (const float*)d_in[8];
    const float* w1    = (const float*)d_in[9];
    const float* b1    = (const float*)d_in[10];
    const float* w2    = (const float*)d_in[11];
    const float* b2    = (const float*)d_in[12];
    const float* wf    = (const float*)d_in[13];
    const float* fbias = (const float*)d_in[14];
    float* out = (float*)d_out;

    char* ws = (char*)d_ws;
    size_t off = 0;
    auto alloc = [&](size_t bytes) {
        char* p = ws + off;
        off = (off + bytes + 255) & ~(size_t)255;
        return p;
    };
    unsigned short* gb     = (unsigned short*)alloc((size_t)GB_ELEMS * 2);      // 17.6 MB
    unsigned short* nbb    = (unsigned short*)alloc((size_t)N_ROWS_P * 16 * 2); // 3.2 MB
    unsigned short* reccat = (unsigned short*)alloc((size_t)N_ROWS_P * 32 * 2); // 6.4 MB
    unsigned short* ligWt  = (unsigned short*)alloc(4096 * 2);
    unsigned short* recWt  = (unsigned short*)alloc(4096 * 2);
    unsigned short* w1t    = (unsigned short*)alloc(16384 * 2);
    unsigned short* w2t    = (unsigned short*)alloc(16384 * 2);
    unsigned short* wft    = (unsigned short*)alloc(98304 * 2);

    hipLaunchKernelGGL(prep_grids, dim3((N_CELLS * 8 + 255) / 256), dim3(256), 0, stream,
                       g0, g1, gb);
    hipLaunchKernelGGL(prep_weights, dim3((139264 + 255) / 256), dim3(256), 0, stream,
                       ligW, recW, w1, w2, wf, ligWt, recWt, w1t, w2t, wft);
    hipLaunchKernelGGL(interp_kernel, dim3((N_PTS * 4 + 255) / 256), dim3(256), 0, stream,
                       pos, nb, gb, nbb, reccat);
    hipLaunchKernelGGL(fused_mlp, dim3(N_ROWS_P / 128), dim3(512), 0, stream,
                       nbb, reccat, ligWt, recWt, w1t, w2t, wft,
                       lig_b, rec_b, b1, b2, fbias, out);
}